// Round 5
// baseline (133.687 us; speedup 1.0000x reference)
//
#include <hip/hip_runtime.h>
#include <math.h>

// Problem: NeuralSplineFourierFilterNNX — tiny MLP on scalar `a` parameterizes a
// degree-3 B-spline; evaluate it at 256^3 fp32 grid points.
//
// Design (fused, single kernel, d_ws untouched):
//   Every block redundantly computes the tiny setup (MLP -> softmax/cumsum knots
//   -> 15 per-segment power-basis cubics via divided differences) into LDS.
//   Grid = 2048 blocks = full residency; redundant setup runs concurrently.
//   Streaming phase: per element: clip, 14-compare branch-free segment search
//   vs register-held boundaries, 5 broadcast-friendly ds_read_b32 (16-word
//   tables over 16 banks -> same-word broadcast, conflict-free: measured
//   SQ_LDS_BANK_CONFLICT=0), 3-FMA Horner in u = xc - t0.
//
//   Round-4 post-mortem: 2-deep prefetch moved the kernel 46 -> <40.6us (out
//   of profile top-5). The harness's 256MiB ws-poison fill flushes L3 every
//   iteration, so ~half of x misses to HBM (~900cy); 2-deep lookahead (~400cy
//   of compute) can't cover that. This round (one isolated change): rotating
//   4-deep prefetch — ~3 iterations (~1100cy) of lookahead, branchless
//   clamped prefetch addresses, named registers (no runtime-indexed arrays).

__device__ __forceinline__ float deboor_eval(float x, int k, const float* t, const float* c) {
    float d[4];
#pragma unroll
    for (int j = 0; j < 4; ++j) d[j] = c[j + k - 3];
#pragma unroll
    for (int r = 1; r <= 3; ++r) {
#pragma unroll
        for (int j = 3; j >= 1; --j) {
            if (j < r) continue;   // constant-folds under unroll
            float tlo = t[j + k - 3];
            float thi = t[j + 1 + k - r];
            float al = (x - tlo) / (thi - tlo);
            d[j] = (1.0f - al) * d[j - 1] + al * d[j];
        }
    }
    return d[3];
}

__global__ __launch_bounds__(256) void spline_fused_kernel(
    const float* __restrict__ x,
    const float* __restrict__ a,  const float* __restrict__ W1, const float* __restrict__ b1,
    const float* __restrict__ W2, const float* __restrict__ b2,
    const float* __restrict__ Ww, const float* __restrict__ bw,
    const float* __restrict__ Wk, const float* __restrict__ bk,
    float* __restrict__ out, int n)
{
    __shared__ float net1[32], net2[32], cpt[18], kl[15], ak[22];
    __shared__ float sB[14], sStart[15], sC0[15], sC1[15], sC2[15], sC3[15];
    int t = threadIdx.x;

    // ---- setup phase (redundant per block; weights total ~6.5 KB, L2-resident) ----
    if (t < 32) net1[t] = sinf(a[0] * W1[t] + b1[t]);
    __syncthreads();

    if (t < 32) {
        float s = b2[t];
#pragma unroll
        for (int i = 0; i < 32; ++i) s += net1[i] * W2[i * 32 + t];
        net2[t] = sinf(s);
    }
    __syncthreads();

    if (t < 17) {                     // control points: w = concat([0], net@Ww+bw)
        float s = bw[t];
#pragma unroll
        for (int i = 0; i < 32; ++i) s += net2[i] * Ww[i * 17 + t];
        cpt[t + 1] = s;
    }
    if (t == 63) cpt[0] = 0.0f;
    if (t >= 32 && t < 47) {          // knot logits
        int j = t - 32;
        float s = bk[j];
#pragma unroll
        for (int i = 0; i < 32; ++i) s += net2[i] * Wk[i * 15 + j];
        kl[j] = s;
    }
    __syncthreads();

    if (t == 0) {                     // softmax + cumsum -> padded knot vector ak[22]
        float m = kl[0];
        for (int j = 1; j < 15; ++j) m = fmaxf(m, kl[j]);
        float sum = 0.0f;
        for (int j = 0; j < 15; ++j) { float e = expf(kl[j] - m); ak[4 + j] = e; sum += e; }
        float inv = 1.0f / sum;
        ak[0] = ak[1] = ak[2] = ak[3] = 0.0f;   // 3 pad zeros + prepended zero knot
        float cum = 0.0f;
        for (int j = 0; j < 15; ++j) { cum += ak[4 + j]; ak[4 + j] = cum * inv; }
        ak[19] = ak[20] = ak[21] = 1.0f;
    }
    __syncthreads();

    if (t < 14) sB[t] = ak[4 + t];    // search boundaries: knots 1..14

    if (t < 15) {                     // segment s: knot-index k = s+3, x in [ak[k], ak[k+1])
        int k = t + 3;
        float t0 = ak[k], t1 = ak[k + 1];
        float dl = (t1 - t0) * (1.0f / 3.0f);
        float f0 = deboor_eval(t0,              k, ak, cpt);
        float f1 = deboor_eval(t0 + dl,         k, ak, cpt);
        float f2 = deboor_eval(t0 + 2.0f * dl,  k, ak, cpt);
        float f3 = deboor_eval(t0 + 3.0f * dl,  k, ak, cpt);
        // Newton divided differences (equispaced, spacing dl) -> power basis in u = x - t0
        float idl  = 1.0f / dl;
        float g01  = (f1 - f0) * idl, g12 = (f2 - f1) * idl, g23 = (f3 - f2) * idl;
        float h012 = (g12 - g01) * (0.5f * idl), h123 = (g23 - g12) * (0.5f * idl);
        float q    = (h123 - h012) * (idl * (1.0f / 3.0f));
        sStart[t] = t0;
        sC0[t]    = f0;
        sC1[t]    = g01 - dl * h012 + 2.0f * dl * dl * q;
        sC2[t]    = h012 - 3.0f * dl * q;
        sC3[t]    = q;
    }
    __syncthreads();

    // ---- streaming phase (memory-bound, latency-hidden via 4-deep prefetch) ----
    float bb[14];                      // block-uniform boundaries in registers
#pragma unroll
    for (int j = 0; j < 14; ++j) bb[j] = sB[j];

    const float kInvSqrt3 = 0.57735026918962576f;
    const float kXMax     = 1.0f - 1e-4f;

    int n4 = n >> 2;
    int gtid = blockIdx.x * blockDim.x + t;
    int stride = gridDim.x * blockDim.x;
    const float4* __restrict__ x4 = (const float4*)x;
    float4* __restrict__ o4 = (float4*)out;

    int i = gtid;
    if (i < n4) {
        int nm1 = n4 - 1;
        // prologue: 4 loads in flight; clamped addresses keep prefetch
        // unconditional (in-bounds re-reads are harmless)
        float4 v0 = x4[i];
        float4 v1 = x4[min(i +     stride, nm1)];
        float4 v2 = x4[min(i + 2 * stride, nm1)];
        float4 v3 = x4[min(i + 3 * stride, nm1)];
        while (true) {
            float in[4] = {v0.x, v0.y, v0.z, v0.w};
            float rr[4];
#pragma unroll
            for (int e = 0; e < 4; ++e) {
                float xc = fminf(fmaxf(in[e] * kInvSqrt3, 0.0f), kXMax);
                int s = 0;
#pragma unroll
                for (int j = 0; j < 14; ++j) s += (xc >= bb[j]) ? 1 : 0;  // searchsorted-right
                float u = xc - sStart[s];
                rr[e] = fmaf(fmaf(fmaf(sC3[s], u, sC2[s]), u, sC1[s]), u, sC0[s]);
            }
            float4 r; r.x = rr[0]; r.y = rr[1]; r.z = rr[2]; r.w = rr[3];
            o4[i] = r;
            int inext = i + stride;
            if (inext >= n4) break;
            i = inext;
            v0 = v1; v1 = v2; v2 = v3;              // rotate pipeline
            v3 = x4[min(i + 3 * stride, nm1)];      // keep 4 loads in flight
        }
    }
    // scalar tail (n % 4 != 0); no-op for 256^3
    for (int i2 = (n4 << 2) + gtid; i2 < n; i2 += stride) {
        float xc = fminf(fmaxf(x[i2] * kInvSqrt3, 0.0f), kXMax);
        int s = 0;
#pragma unroll
        for (int j = 0; j < 14; ++j) s += (xc >= bb[j]) ? 1 : 0;
        float u = xc - sStart[s];
        out[i2] = fmaf(fmaf(fmaf(sC3[s], u, sC2[s]), u, sC1[s]), u, sC0[s]);
    }
}

extern "C" void kernel_launch(void* const* d_in, const int* in_sizes, int n_in,
                              void* d_out, int out_size, void* d_ws, size_t ws_size,
                              hipStream_t stream)
{
    const float* x  = (const float*)d_in[0];
    const float* a  = (const float*)d_in[1];
    const float* W1 = (const float*)d_in[2];
    const float* b1 = (const float*)d_in[3];
    const float* W2 = (const float*)d_in[4];
    const float* b2 = (const float*)d_in[5];
    const float* Ww = (const float*)d_in[6];
    const float* bw = (const float*)d_in[7];
    const float* Wk = (const float*)d_in[8];
    const float* bk = (const float*)d_in[9];
    float* out = (float*)d_out;

    (void)d_ws; (void)ws_size;  // workspace intentionally unused (avoids ws re-poison traffic)
    spline_fused_kernel<<<2048, 256, 0, stream>>>(x, a, W1, b1, W2, b2, Ww, bw, Wk, bk,
                                                  out, out_size);
}

// Round 6
// 131.687 us; speedup vs baseline: 1.0152x; 1.0152x over previous
//
#include <hip/hip_runtime.h>
#include <math.h>

// Problem: NeuralSplineFourierFilterNNX — tiny MLP on scalar `a` parameterizes a
// degree-3 B-spline; evaluate it at 256^3 fp32 grid points.
//
// Design (fused, single kernel, d_ws untouched):
//   Every block redundantly computes the tiny setup (MLP -> softmax/cumsum knots
//   -> 15 per-segment power-basis cubics via divided differences) into LDS.
//   Grid = 2048 blocks = full residency; redundant setup runs concurrently.
//   Streaming phase: per element: clip, 14-compare branch-free segment search
//   vs register-held boundaries, 5 broadcast-friendly ds_read_b32 (16-word
//   tables over 16 banks -> same-word broadcast, conflict-free: measured
//   SQ_LDS_BANK_CONFLICT=0), 3-FMA Horner in u = xc - t0.
//
// Session ledger (kernel-time per rocprof):
//   r1 baseline fused, no prefetch:            45.9-49.1 us
//   r3 b128-pack + 4-wide batch:               60.4-62.0 us  (REGRESSED: lost
//      broadcast LDS pattern, VGPR 32->56, occupancy halved)
//   r4 2-deep conditional prefetch (THIS):     <40.6 us      (best)
//   r5 4-deep clamped rotating prefetch:       46.2-47.1 us  (REGRESSED: VGPR
//      stayed 32 -> compiler sank the unconditional loads to use points,
//      defeating the pipeline; conditional top-of-body form below is the one
//      the compiler keeps as a real 2-deep pipeline)
//   e2e is dominated by ~90us of harness poison fills (256MiB ws fill runs
//   every iteration regardless of ws use); kernel is ~0.3x exposed.

__device__ __forceinline__ float deboor_eval(float x, int k, const float* t, const float* c) {
    float d[4];
#pragma unroll
    for (int j = 0; j < 4; ++j) d[j] = c[j + k - 3];
#pragma unroll
    for (int r = 1; r <= 3; ++r) {
#pragma unroll
        for (int j = 3; j >= 1; --j) {
            if (j < r) continue;   // constant-folds under unroll
            float tlo = t[j + k - 3];
            float thi = t[j + 1 + k - r];
            float al = (x - tlo) / (thi - tlo);
            d[j] = (1.0f - al) * d[j - 1] + al * d[j];
        }
    }
    return d[3];
}

__global__ __launch_bounds__(256) void spline_fused_kernel(
    const float* __restrict__ x,
    const float* __restrict__ a,  const float* __restrict__ W1, const float* __restrict__ b1,
    const float* __restrict__ W2, const float* __restrict__ b2,
    const float* __restrict__ Ww, const float* __restrict__ bw,
    const float* __restrict__ Wk, const float* __restrict__ bk,
    float* __restrict__ out, int n)
{
    __shared__ float net1[32], net2[32], cpt[18], kl[15], ak[22];
    __shared__ float sB[14], sStart[15], sC0[15], sC1[15], sC2[15], sC3[15];
    int t = threadIdx.x;

    // ---- setup phase (redundant per block; weights total ~6.5 KB, L2-resident) ----
    if (t < 32) net1[t] = sinf(a[0] * W1[t] + b1[t]);
    __syncthreads();

    if (t < 32) {
        float s = b2[t];
#pragma unroll
        for (int i = 0; i < 32; ++i) s += net1[i] * W2[i * 32 + t];
        net2[t] = sinf(s);
    }
    __syncthreads();

    if (t < 17) {                     // control points: w = concat([0], net@Ww+bw)
        float s = bw[t];
#pragma unroll
        for (int i = 0; i < 32; ++i) s += net2[i] * Ww[i * 17 + t];
        cpt[t + 1] = s;
    }
    if (t == 63) cpt[0] = 0.0f;
    if (t >= 32 && t < 47) {          // knot logits
        int j = t - 32;
        float s = bk[j];
#pragma unroll
        for (int i = 0; i < 32; ++i) s += net2[i] * Wk[i * 15 + j];
        kl[j] = s;
    }
    __syncthreads();

    if (t == 0) {                     // softmax + cumsum -> padded knot vector ak[22]
        float m = kl[0];
        for (int j = 1; j < 15; ++j) m = fmaxf(m, kl[j]);
        float sum = 0.0f;
        for (int j = 0; j < 15; ++j) { float e = expf(kl[j] - m); ak[4 + j] = e; sum += e; }
        float inv = 1.0f / sum;
        ak[0] = ak[1] = ak[2] = ak[3] = 0.0f;   // 3 pad zeros + prepended zero knot
        float cum = 0.0f;
        for (int j = 0; j < 15; ++j) { cum += ak[4 + j]; ak[4 + j] = cum * inv; }
        ak[19] = ak[20] = ak[21] = 1.0f;
    }
    __syncthreads();

    if (t < 14) sB[t] = ak[4 + t];    // search boundaries: knots 1..14

    if (t < 15) {                     // segment s: knot-index k = s+3, x in [ak[k], ak[k+1])
        int k = t + 3;
        float t0 = ak[k], t1 = ak[k + 1];
        float dl = (t1 - t0) * (1.0f / 3.0f);
        float f0 = deboor_eval(t0,              k, ak, cpt);
        float f1 = deboor_eval(t0 + dl,         k, ak, cpt);
        float f2 = deboor_eval(t0 + 2.0f * dl,  k, ak, cpt);
        float f3 = deboor_eval(t0 + 3.0f * dl,  k, ak, cpt);
        // Newton divided differences (equispaced, spacing dl) -> power basis in u = x - t0
        float idl  = 1.0f / dl;
        float g01  = (f1 - f0) * idl, g12 = (f2 - f1) * idl, g23 = (f3 - f2) * idl;
        float h012 = (g12 - g01) * (0.5f * idl), h123 = (g23 - g12) * (0.5f * idl);
        float q    = (h123 - h012) * (idl * (1.0f / 3.0f));
        sStart[t] = t0;
        sC0[t]    = f0;
        sC1[t]    = g01 - dl * h012 + 2.0f * dl * dl * q;
        sC2[t]    = h012 - 3.0f * dl * q;
        sC3[t]    = q;
    }
    __syncthreads();

    // ---- streaming phase (memory-bound, latency-hidden via 2-deep prefetch) ----
    float bb[14];                      // block-uniform boundaries in registers
#pragma unroll
    for (int j = 0; j < 14; ++j) bb[j] = sB[j];

    const float kInvSqrt3 = 0.57735026918962576f;
    const float kXMax     = 1.0f - 1e-4f;

    int n4 = n >> 2;
    int gtid = blockIdx.x * blockDim.x + t;
    int stride = gridDim.x * blockDim.x;
    const float4* __restrict__ x4 = (const float4*)x;
    float4* __restrict__ o4 = (float4*)out;

    int i = gtid;
    if (i < n4) {
        float4 v = x4[i];
        while (true) {
            int inext = i + stride;
            bool more = inext < n4;
            float4 vn;
            if (more) vn = x4[inext];          // prefetch issued before compute on v
            float in[4] = {v.x, v.y, v.z, v.w};
            float rr[4];
#pragma unroll
            for (int e = 0; e < 4; ++e) {
                float xc = fminf(fmaxf(in[e] * kInvSqrt3, 0.0f), kXMax);
                int s = 0;
#pragma unroll
                for (int j = 0; j < 14; ++j) s += (xc >= bb[j]) ? 1 : 0;  // searchsorted-right
                float u = xc - sStart[s];
                rr[e] = fmaf(fmaf(fmaf(sC3[s], u, sC2[s]), u, sC1[s]), u, sC0[s]);
            }
            float4 r; r.x = rr[0]; r.y = rr[1]; r.z = rr[2]; r.w = rr[3];
            o4[i] = r;
            if (!more) break;
            v = vn; i = inext;
        }
    }
    // scalar tail (n % 4 != 0); no-op for 256^3
    for (int i2 = (n4 << 2) + gtid; i2 < n; i2 += stride) {
        float xc = fminf(fmaxf(x[i2] * kInvSqrt3, 0.0f), kXMax);
        int s = 0;
#pragma unroll
        for (int j = 0; j < 14; ++j) s += (xc >= bb[j]) ? 1 : 0;
        float u = xc - sStart[s];
        out[i2] = fmaf(fmaf(fmaf(sC3[s], u, sC2[s]), u, sC1[s]), u, sC0[s]);
    }
}

extern "C" void kernel_launch(void* const* d_in, const int* in_sizes, int n_in,
                              void* d_out, int out_size, void* d_ws, size_t ws_size,
                              hipStream_t stream)
{
    const float* x  = (const float*)d_in[0];
    const float* a  = (const float*)d_in[1];
    const float* W1 = (const float*)d_in[2];
    const float* b1 = (const float*)d_in[3];
    const float* W2 = (const float*)d_in[4];
    const float* b2 = (const float*)d_in[5];
    const float* Ww = (const float*)d_in[6];
    const float* bw = (const float*)d_in[7];
    const float* Wk = (const float*)d_in[8];
    const float* bk = (const float*)d_in[9];
    float* out = (float*)d_out;

    (void)d_ws; (void)ws_size;  // workspace intentionally unused
    spline_fused_kernel<<<2048, 256, 0, stream>>>(x, a, W1, b1, W2, b2, Ww, bw, Wk, bk,
                                                  out, out_size);
}